// Round 9
// baseline (3745.702 us; speedup 1.0000x reference)
//
#include <hip/hip_runtime.h>

typedef _Float16 half8 __attribute__((ext_vector_type(8)));
typedef _Float16 half4 __attribute__((ext_vector_type(4)));
typedef float    floatx4 __attribute__((ext_vector_type(4)));
typedef float    float4v __attribute__((ext_vector_type(4)));

#define BB 8
#define NN 2048
#define DD 512

// MFMA fragment mapping (gfx950, 16x16x32, m89/m91/m120-verified):
//   A-operand: A[m = lane&15][k = (lane>>4)*8 + j], j=0..7 contiguous
//   B-operand: B[n = lane&15][k = (lane>>4)*8 + j]   (NT: both contiguous in k)
//   C/D:       col = lane&15, row = (lane>>4)*4 + reg
//
// R9: scores & pv are REGISTER-DIRECT (no LDS, no __syncthreads): k is
// contiguous in both operands, so each lane's fragment is one
// global_load_dwordx4 at row (base+lr), offset kt*32+quad*8.  Register
// double-buffer pipelines loads across k-steps; waves run barrier-free
// (the m97 2-barrier structure's vmcnt(0) drain was the 8%-MfmaUtil cap).
// projqk/projv keep m97 global_load_lds staging (XOR swizzle, 0 conflicts).
//
// Length-aware sparsity: only the (q<L)x(k<L) region is computed.  Rows
// q>=L get mean(v) exactly via mean_v = Wv*mean_x + bv (linearity).

__device__ __forceinline__ void stage_tile(const _Float16* __restrict__ g,
                                           int gstride, _Float16* lds,
                                           int w, int lane)
{
#pragma unroll
    for (int j = 0; j < 2; ++j) {
        int grp = w * 2 + j;                      // 16-row group 0..7
        int r   = grp * 16 + (lane >> 2);         // 0..127
        int cb  = (lane & 3) ^ ((r >> 1) & 3);    // logical 16B block to fetch
        const _Float16* gp = g + (size_t)r * gstride + cb * 8;
        _Float16* lp = lds + grp * 512;           // wave-uniform base
        __builtin_amdgcn_global_load_lds(
            (const __attribute__((address_space(1))) void*)gp,
            (__attribute__((address_space(3))) void*)lp, 16, 0, 0);
    }
}

__device__ __forceinline__ half8 frag(const _Float16* tile, int m, int quad)
{
    return *(const half8*)&tile[m * 32 + ((quad ^ ((m >> 1) & 3)) * 8)];
}

// ---------------------------------------------------------------------------
// Kernel 0: prep — fp16 copies of x, Wq, Wk, Wv.  x rows >= ceil128(L) are
// never read by projqk/projv -> skipped.
// ---------------------------------------------------------------------------
__global__ __launch_bounds__(256) void prep_kernel(
    const float* __restrict__ x, const float* __restrict__ Wq,
    const float* __restrict__ Wk, const float* __restrict__ Wv,
    const int* __restrict__ lens,
    _Float16* __restrict__ xh, _Float16* __restrict__ wqh,
    _Float16* __restrict__ wkh, _Float16* __restrict__ wvh)
{
    const int XQ = (BB * NN * DD) / 4;   // 2097152 float4s
    const int WQ = (DD * DD) / 4;        // 65536
    int t = blockIdx.x * 256 + threadIdx.x;
    const float* src; _Float16* dst; int i;
    if (t < XQ) {
        int row = t >> 7;                // 128 float4 per row
        int b   = row >> 11;
        if ((row & 2047) >= ((lens[b] + 127) & ~127)) return;
        src = x;  dst = xh;  i = t;
    }
    else if (t < XQ + WQ)   { src = Wq; dst = wqh; i = t - XQ; }
    else if (t < XQ + 2*WQ) { src = Wk; dst = wkh; i = t - XQ - WQ; }
    else if (t < XQ + 3*WQ) { src = Wv; dst = wvh; i = t - XQ - 2*WQ; }
    else return;
    float4v f = *(const float4v*)&src[(size_t)i * 4];
    half4 h;
    for (int j = 0; j < 4; ++j) h[j] = (_Float16)f[j];
    *(half4*)&dst[(size_t)i * 4] = h;
}

// ---------------------------------------------------------------------------
// Kernel 0b: column sums of x (fp32, exact): sx[b][d] = sum_n x[b][n][d].
// 1024 blocks (16 rows each) for occupancy; sx pre-zeroed by memset.
// ---------------------------------------------------------------------------
__global__ __launch_bounds__(256) void meanx_kernel(
    const float* __restrict__ x, float* __restrict__ sx)
{
    const int b  = blockIdx.y;
    const int n0 = blockIdx.x * 16;
    const int d0 = threadIdx.x;          // cols d0 and d0+256
    float s0 = 0.f, s1 = 0.f;
    const float* base = x + ((size_t)b * NN + n0) * DD;
#pragma unroll
    for (int n = 0; n < 16; ++n) {
        s0 += base[n * DD + d0];
        s1 += base[n * DD + d0 + 256];
    }
    atomicAdd(&sx[b * DD + d0], s0);
    atomicAdd(&sx[b * DD + d0 + 256], s1);
}

// ---------------------------------------------------------------------------
// Kernel 0c: mean_v[b][e] = Wv[e,:].(sx[b,:]/2048) + bv[e]  (fp32 exact).
// ---------------------------------------------------------------------------
__global__ __launch_bounds__(256) void mvgemv_kernel(
    const float* __restrict__ Wv, const float* __restrict__ bv,
    const float* __restrict__ sx, float* __restrict__ mean_v)
{
    const int blk = blockIdx.x;          // 0..1023
    const int b   = blk >> 7;
    const int e   = (blk & 127) * 4 + (threadIdx.x >> 6);
    const int lane = threadIdx.x & 63;
    const float* wr = Wv + (size_t)e * DD + lane * 8;
    const float* xr = sx + b * DD + lane * 8;
    float s = 0.f;
    for (int j = 0; j < 8; ++j) s += wr[j] * xr[j];
    for (int off = 32; off > 0; off >>= 1) s += __shfl_xor(s, off);
    if (lane == 0)
        mean_v[b * DD + e] = s * (1.0f / 2048.0f) + bv[e];
}

// ---------------------------------------------------------------------------
// Kernel 1: Q/K projection (fp16 inputs, m97 staging).
// ---------------------------------------------------------------------------
__global__ __launch_bounds__(256) void projqk_kernel(
    const _Float16* __restrict__ xh,
    const _Float16* __restrict__ wqh, const _Float16* __restrict__ wkh,
    const float* __restrict__ bq, const float* __restrict__ bk,
    const int* __restrict__ lens,
    _Float16* __restrict__ qb, _Float16* __restrict__ kb)
{
    const int z = blockIdx.z;                       // 0=q 1=k
    const int r0 = blockIdx.y * 128;                // global row in [0,16384)
    const int bb = r0 >> 11;                        // batch
    if ((r0 & 2047) >= lens[bb]) return;            // rows never read
    const _Float16* Wh  = z ? wkh : wqh;
    const float*    bias= z ? bk  : bq;
    _Float16*       outp= z ? kb  : qb;
    const int c0 = blockIdx.x * 128;

    __shared__ __align__(16) _Float16 As[128 * 32];
    __shared__ __align__(16) _Float16 Bs[128 * 32];

    const int tid  = threadIdx.x;
    const int lane = tid & 63;
    const int w    = tid >> 6;
    const int wm   = w >> 1, wn = w & 1;
    const int lr   = lane & 15;
    const int quad = lane >> 4;

    floatx4 zero; zero[0]=0.f; zero[1]=0.f; zero[2]=0.f; zero[3]=0.f;
    floatx4 acc[4][4];
    for (int i = 0; i < 4; ++i)
        for (int j = 0; j < 4; ++j) acc[i][j] = zero;

    for (int kt = 0; kt < DD / 32; ++kt) {
        __syncthreads();
        stage_tile(xh + (size_t)r0 * DD + kt * 32, DD, As, w, lane);
        stage_tile(Wh + (size_t)c0 * DD + kt * 32, DD, Bs, w, lane);
        __syncthreads();
        half8 a[4], b[4];
        for (int mt = 0; mt < 4; ++mt) a[mt] = frag(As, wm * 64 + mt * 16 + lr, quad);
        for (int nt = 0; nt < 4; ++nt) b[nt] = frag(Bs, wn * 64 + nt * 16 + lr, quad);
        for (int mt = 0; mt < 4; ++mt)
            for (int nt = 0; nt < 4; ++nt)
                acc[mt][nt] = __builtin_amdgcn_mfma_f32_16x16x32_f16(a[mt], b[nt], acc[mt][nt], 0, 0, 0);
    }

    for (int mt = 0; mt < 4; ++mt)
        for (int nt = 0; nt < 4; ++nt)
            for (int r = 0; r < 4; ++r) {
                int row = r0 + wm * 64 + mt * 16 + quad * 4 + r;
                int col = c0 + wn * 64 + nt * 16 + lr;
                outp[(size_t)row * DD + col] = (_Float16)(acc[mt][nt][r] + bias[col]);
            }
}

// ---------------------------------------------------------------------------
// Kernel 1b: V projection, TRANSPOSED output, tiles with n0 < L only.
// ---------------------------------------------------------------------------
__global__ __launch_bounds__(256) void projv_kernel(
    const _Float16* __restrict__ xh,
    const _Float16* __restrict__ wvh, const float* __restrict__ bv,
    const int* __restrict__ lens, _Float16* __restrict__ vhT)
{
    const int b  = blockIdx.z;
    const int e0 = blockIdx.y * 128;
    const int n0 = blockIdx.x * 128;
    if (n0 >= lens[b]) return;

    __shared__ __align__(16) _Float16 As[128 * 32];
    __shared__ __align__(16) _Float16 Bs[128 * 32];

    const int tid  = threadIdx.x;
    const int lane = tid & 63;
    const int w    = tid >> 6;
    const int wm   = w >> 1, wn = w & 1;
    const int lr   = lane & 15;
    const int quad = lane >> 4;

    floatx4 zero; zero[0]=0.f; zero[1]=0.f; zero[2]=0.f; zero[3]=0.f;
    floatx4 acc[4][4];
    for (int i = 0; i < 4; ++i)
        for (int j = 0; j < 4; ++j) acc[i][j] = zero;

    for (int kt = 0; kt < DD / 32; ++kt) {
        __syncthreads();
        stage_tile(wvh + (size_t)e0 * DD + kt * 32, DD, As, w, lane);
        stage_tile(xh + ((size_t)b * NN + n0) * DD + kt * 32, DD, Bs, w, lane);
        __syncthreads();
        half8 a[4], bfr[4];
        for (int mt = 0; mt < 4; ++mt) a[mt]   = frag(As, wm * 64 + mt * 16 + lr, quad);
        for (int nt = 0; nt < 4; ++nt) bfr[nt] = frag(Bs, wn * 64 + nt * 16 + lr, quad);
        for (int mt = 0; mt < 4; ++mt)
            for (int nt = 0; nt < 4; ++nt)
                acc[mt][nt] = __builtin_amdgcn_mfma_f32_16x16x32_f16(a[mt], bfr[nt], acc[mt][nt], 0, 0, 0);
    }

    for (int mt = 0; mt < 4; ++mt)
        for (int nt = 0; nt < 4; ++nt)
            for (int r = 0; r < 4; ++r) {
                int e = e0 + wm * 64 + mt * 16 + quad * 4 + r;
                int n = n0 + wn * 64 + nt * 16 + lr;
                vhT[((size_t)b * DD + e) * NN + n] = (_Float16)(acc[mt][nt][r] + bv[e]);
            }
}

// ---------------------------------------------------------------------------
// Kernel 2: S = (Q.K^T)/sqrt(512) -> fp16.  REGISTER-DIRECT, barrier-free:
// per k-step each lane loads its 8 fragments (dwordx4) straight to VGPRs;
// register double-buffer pipelines the next step's loads under the MFMAs.
// ---------------------------------------------------------------------------
__global__ __launch_bounds__(256) void scores_kernel(
    const _Float16* __restrict__ qb, const _Float16* __restrict__ kb,
    const int* __restrict__ lens, _Float16* __restrict__ S)
{
    const int b  = blockIdx.z;
    const int r0 = blockIdx.y * 128;
    const int c0 = blockIdx.x * 128;
    const int L  = lens[b];
    if (r0 >= L || c0 >= L) return;

    const int tid  = threadIdx.x;
    const int lane = tid & 63;
    const int w    = tid >> 6;
    const int wm   = w >> 1, wn = w & 1;
    const int lr   = lane & 15;
    const int quad = lane >> 4;

    const _Float16* Ap = qb + ((size_t)b * NN + r0 + wm * 64 + lr) * DD + quad * 8;
    const _Float16* Bp = kb + ((size_t)b * NN + c0 + wn * 64 + lr) * DD + quad * 8;

    floatx4 zero; zero[0]=0.f; zero[1]=0.f; zero[2]=0.f; zero[3]=0.f;
    floatx4 acc[4][4];
    for (int i = 0; i < 4; ++i)
        for (int j = 0; j < 4; ++j) acc[i][j] = zero;

    half8 a[2][4], bf[2][4];
#pragma unroll
    for (int mt = 0; mt < 4; ++mt) a[0][mt]  = *(const half8*)&Ap[(size_t)(mt * 16) * DD];
#pragma unroll
    for (int nt = 0; nt < 4; ++nt) bf[0][nt] = *(const half8*)&Bp[(size_t)(nt * 16) * DD];

    for (int kt = 0; kt < DD / 32; ++kt) {
        const int cur = kt & 1;
        if (kt + 1 < DD / 32) {
#pragma unroll
            for (int mt = 0; mt < 4; ++mt)
                a[cur ^ 1][mt]  = *(const half8*)&Ap[(size_t)(mt * 16) * DD + (kt + 1) * 32];
#pragma unroll
            for (int nt = 0; nt < 4; ++nt)
                bf[cur ^ 1][nt] = *(const half8*)&Bp[(size_t)(nt * 16) * DD + (kt + 1) * 32];
        }
#pragma unroll
        for (int mt = 0; mt < 4; ++mt)
#pragma unroll
            for (int nt = 0; nt < 4; ++nt)
                acc[mt][nt] = __builtin_amdgcn_mfma_f32_16x16x32_f16(a[cur][mt], bf[cur][nt], acc[mt][nt], 0, 0, 0);
    }

    const float scale = 0.044194173824159216f;   // 1/sqrt(512)
    for (int mt = 0; mt < 4; ++mt)
        for (int nt = 0; nt < 4; ++nt)
            for (int r = 0; r < 4; ++r) {
                int q    = r0 + wm * 64 + mt * 16 + quad * 4 + r;
                int kcol = c0 + wn * 64 + nt * 16 + lr;
                S[((size_t)b * NN + q) * NN + kcol] = (_Float16)(acc[mt][nt][r] * scale);
            }
}

// ---------------------------------------------------------------------------
// Kernel 3: in-place row softmax, rows q<L, keys k<L; writes P=0 for
// k in [L, ceil32(L)) so pv's last K-chunk is clean.
// ---------------------------------------------------------------------------
__global__ __launch_bounds__(256) void softmax_kernel(
    _Float16* __restrict__ S, const int* __restrict__ lens)
{
    const int b = blockIdx.y, q = blockIdx.x;
    const int L = lens[b];
    if (q >= L) return;
    const int Lp32 = (L + 31) & ~31;
    const size_t base = ((size_t)b * NN + q) * NN;
    const int tid  = threadIdx.x;
    const int lane = tid & 63;
    const int w    = tid >> 6;
    const int k0   = tid * 8;
    const bool active = k0 < Lp32;
    const float NEG = -__builtin_huge_valf();

    float f[8];
    if (active) {
        half8 v = *(const half8*)&S[base + k0];
        for (int j = 0; j < 8; ++j) f[j] = (k0 + j < L) ? (float)v[j] : NEG;
    } else {
        for (int j = 0; j < 8; ++j) f[j] = NEG;
    }

    float m = f[0];
    for (int j = 1; j < 8; ++j) m = fmaxf(m, f[j]);
    for (int off = 32; off > 0; off >>= 1) m = fmaxf(m, __shfl_xor(m, off));
    __shared__ float redm[4];
    __shared__ float reds[4];
    if (lane == 0) redm[w] = m;
    __syncthreads();
    m = fmaxf(fmaxf(redm[0], redm[1]), fmaxf(redm[2], redm[3]));

    float e[8], s = 0.f;
    for (int j = 0; j < 8; ++j) { e[j] = __expf(f[j] - m); s += e[j]; }  // exp(-inf)=0
    for (int off = 32; off > 0; off >>= 1) s += __shfl_xor(s, off);
    if (lane == 0) reds[w] = s;
    __syncthreads();
    s = (reds[0] + reds[1]) + (reds[2] + reds[3]);

    float inv = 1.0f / s;
    if (active) {
        half8 o;
        for (int j = 0; j < 8; ++j) o[j] = (_Float16)(e[j] * inv);
        *(half8*)&S[base + k0] = o;
    }
}

// ---------------------------------------------------------------------------
// Kernel 4: O[b][q][e] = sum_{k<L} P[b][q][k] * Vt[b][e][k] for q<L;
// mean_v for q>=L.  REGISTER-DIRECT, barrier-free (see scores).  64-row
// q-tiles; wave w owns e-cols c0+32w..+31.
// ---------------------------------------------------------------------------
__global__ __launch_bounds__(256) void pv_kernel(
    const _Float16* __restrict__ P, const _Float16* __restrict__ vhT,
    const int* __restrict__ lens, const float* __restrict__ mean_v,
    float* __restrict__ out)
{
    const int b  = blockIdx.z;
    const int L  = lens[b];
    const int r0 = blockIdx.y * 64;    // q rows
    const int c0 = blockIdx.x * 128;   // e cols
    const int KT = (r0 < L) ? ((L + 31) >> 5) : 0;

    const int tid  = threadIdx.x;
    const int lane = tid & 63;
    const int w    = tid >> 6;
    const int lr   = lane & 15;
    const int quad = lane >> 4;

    const _Float16* Ap = P   + ((size_t)b * NN + r0 + lr) * NN + quad * 8;
    const _Float16* Bp = vhT + ((size_t)b * DD + c0 + w * 32 + lr) * NN + quad * 8;

    floatx4 zero; zero[0]=0.f; zero[1]=0.f; zero[2]=0.f; zero[3]=0.f;
    floatx4 acc[4][2];
    for (int i = 0; i < 4; ++i)
        for (int j = 0; j < 2; ++j) acc[i][j] = zero;

    half8 a[2][4], bf[2][2];
    if (KT > 0) {
#pragma unroll
        for (int mt = 0; mt < 4; ++mt) a[0][mt]  = *(const half8*)&Ap[(size_t)(mt * 16) * NN];
#pragma unroll
        for (int nt = 0; nt < 2; ++nt) bf[0][nt] = *(const half8*)&Bp[(size_t)(nt * 16) * NN];
    }
    for (int kt = 0; kt < KT; ++kt) {
        const int cur = kt & 1;
        if (kt + 1 < KT) {
#pragma unroll
            for (int mt = 0; mt < 4; ++mt)
                a[cur ^ 1][mt]  = *(const half8*)&Ap[(size_t)(mt * 16) * NN + (kt + 1) * 32];
#pragma unroll
            for (int nt = 0; nt < 2; ++nt)
                bf[cur ^ 1][nt] = *(const half8*)&Bp[(size_t)(nt * 16) * NN + (kt + 1) * 32];
        }
#pragma unroll
        for (int mt = 0; mt < 4; ++mt)
#pragma unroll
            for (int nt = 0; nt < 2; ++nt)
                acc[mt][nt] = __builtin_amdgcn_mfma_f32_16x16x32_f16(a[cur][mt], bf[cur][nt], acc[mt][nt], 0, 0, 0);
    }

    float mval[2];
    for (int nt = 0; nt < 2; ++nt)
        mval[nt] = mean_v[b * DD + c0 + w * 32 + nt * 16 + lr];

    for (int mt = 0; mt < 4; ++mt)
        for (int nt = 0; nt < 2; ++nt)
            for (int r = 0; r < 4; ++r) {
                int q = r0 + mt * 16 + quad * 4 + r;
                int e = c0 + w * 32 + nt * 16 + lr;
                float val = (q < L) ? acc[mt][nt][r] : mval[nt];
                out[((size_t)b * NN + q) * DD + e] = val;
            }
}

// ---------------------------------------------------------------------------
extern "C" void kernel_launch(void* const* d_in, const int* in_sizes, int n_in,
                              void* d_out, int out_size, void* d_ws, size_t ws_size,
                              hipStream_t stream) {
    const float* x    = (const float*)d_in[0];
    const int*   lens = (const int*)d_in[1];   // harness delivers integer inputs as int32
    const float* Wq   = (const float*)d_in[2];
    const float* bq   = (const float*)d_in[3];
    const float* Wk   = (const float*)d_in[4];
    const float* bk   = (const float*)d_in[5];
    const float* Wv   = (const float*)d_in[6];
    const float* bv   = (const float*)d_in[7];
    float* out = (float*)d_out;

    // workspace layout (128 MiB):
    //   0: qb (16M) | 16M: kb (16M) | 32M: vhT (16M)
    //   48M: mean_v (16KB) | 48M+64K: sx (16KB)
    //   64M: S (64M) — first ~18M overlaid by [xh 16M | wqh | wkh | wvh],
    //        dead before scores_kernel writes S (stream-ordered).
    char* ws = (char*)d_ws;
    const size_t MB = 1024 * 1024;
    _Float16* qb  = (_Float16*)(ws);
    _Float16* kb  = (_Float16*)(ws + 16 * MB);
    _Float16* vh  = (_Float16*)(ws + 32 * MB);
    float*    mv  = (float*)   (ws + 48 * MB);
    float*    sx  = (float*)   (ws + 48 * MB + 64 * 1024);
    _Float16* S   = (_Float16*)(ws + 64 * MB);
    _Float16* xh  = (_Float16*)(ws + 64 * MB);
    _Float16* wqh = (_Float16*)(ws + 80 * MB);
    _Float16* wkh = (_Float16*)(ws + 80 * MB + 512 * 1024);
    _Float16* wvh = (_Float16*)(ws + 81 * MB);

    hipMemsetAsync(sx, 0, BB * DD * sizeof(float), stream);
    prep_kernel  <<<8960, 256, 0, stream>>>(x, Wq, Wk, Wv, lens, xh, wqh, wkh, wvh);
    meanx_kernel <<<dim3(128, 8),    256, 0, stream>>>(x, sx);
    mvgemv_kernel<<<1024,            256, 0, stream>>>(Wv, bv, sx, mv);
    projqk_kernel<<<dim3(4, 128, 2), 256, 0, stream>>>(xh, wqh, wkh, bq, bk, lens, qb, kb);
    projv_kernel <<<dim3(16, 4, 8),  256, 0, stream>>>(xh, wvh, bv, lens, vh);
    scores_kernel<<<dim3(16, 16, 8), 256, 0, stream>>>(qb, kb, lens, S);
    softmax_kernel<<<dim3(2048, 8),  256, 0, stream>>>(S, lens);
    pv_kernel    <<<dim3(4, 32, 8),  256, 0, stream>>>(S, vh, lens, mv, out);
}

// Round 10
// 325.120 us; speedup vs baseline: 11.5210x; 11.5210x over previous
//
#include <hip/hip_runtime.h>

typedef _Float16 half8 __attribute__((ext_vector_type(8)));
typedef _Float16 half4 __attribute__((ext_vector_type(4)));
typedef float    floatx4 __attribute__((ext_vector_type(4)));
typedef float    float4v __attribute__((ext_vector_type(4)));

#define BB 8
#define NN 2048
#define DD 512

// MFMA fragment mapping (gfx950, 16x16x32, m89/m91/m120-verified):
//   A-operand: A[m = lane&15][k = (lane>>4)*8 + j], j=0..7 contiguous
//   B-operand: B[n = lane&15][k = (lane>>4)*8 + j]   (NT: both contiguous in k)
//   C/D:       col = lane&15, row = (lane>>4)*4 + reg
//
// scores & pv: REGISTER-DIRECT (no LDS, no __syncthreads).  R9 post-mortem:
// fragment buffers indexed by a loop-dependent `cur` in a runtime-trip-count
// loop were spilled to scratch (VGPR=80, 5ms).  R10: explicit unroll-by-2
// with named buffer sets -> all indices static -> fragments stay in VGPRs.
// projqk/projv keep m97 global_load_lds staging (XOR swizzle, 0 conflicts).
//
// Length-aware sparsity: only the (q<L)x(k<L) region is computed.  Rows
// q>=L get mean(v) exactly via mean_v = Wv*mean_x + bv (linearity).

__device__ __forceinline__ void stage_tile(const _Float16* __restrict__ g,
                                           int gstride, _Float16* lds,
                                           int w, int lane)
{
#pragma unroll
    for (int j = 0; j < 2; ++j) {
        int grp = w * 2 + j;                      // 16-row group 0..7
        int r   = grp * 16 + (lane >> 2);         // 0..127
        int cb  = (lane & 3) ^ ((r >> 1) & 3);    // logical 16B block to fetch
        const _Float16* gp = g + (size_t)r * gstride + cb * 8;
        _Float16* lp = lds + grp * 512;           // wave-uniform base
        __builtin_amdgcn_global_load_lds(
            (const __attribute__((address_space(1))) void*)gp,
            (__attribute__((address_space(3))) void*)lp, 16, 0, 0);
    }
}

__device__ __forceinline__ half8 frag(const _Float16* tile, int m, int quad)
{
    return *(const half8*)&tile[m * 32 + ((quad ^ ((m >> 1) & 3)) * 8)];
}

// ---------------------------------------------------------------------------
// Kernel 0: prep — fp16 copies of x, Wq, Wk, Wv.  x rows >= ceil128(L) are
// never read by projqk/projv -> skipped.
// ---------------------------------------------------------------------------
__global__ __launch_bounds__(256) void prep_kernel(
    const float* __restrict__ x, const float* __restrict__ Wq,
    const float* __restrict__ Wk, const float* __restrict__ Wv,
    const int* __restrict__ lens,
    _Float16* __restrict__ xh, _Float16* __restrict__ wqh,
    _Float16* __restrict__ wkh, _Float16* __restrict__ wvh)
{
    const int XQ = (BB * NN * DD) / 4;   // 2097152 float4s
    const int WQ = (DD * DD) / 4;        // 65536
    int t = blockIdx.x * 256 + threadIdx.x;
    const float* src; _Float16* dst; int i;
    if (t < XQ) {
        int row = t >> 7;                // 128 float4 per row
        int b   = row >> 11;
        if ((row & 2047) >= ((lens[b] + 127) & ~127)) return;
        src = x;  dst = xh;  i = t;
    }
    else if (t < XQ + WQ)   { src = Wq; dst = wqh; i = t - XQ; }
    else if (t < XQ + 2*WQ) { src = Wk; dst = wkh; i = t - XQ - WQ; }
    else if (t < XQ + 3*WQ) { src = Wv; dst = wvh; i = t - XQ - 2*WQ; }
    else return;
    float4v f = *(const float4v*)&src[(size_t)i * 4];
    half4 h;
    for (int j = 0; j < 4; ++j) h[j] = (_Float16)f[j];
    *(half4*)&dst[(size_t)i * 4] = h;
}

// ---------------------------------------------------------------------------
// Kernel 0b: column sums of x (fp32, exact): sx[b][d] = sum_n x[b][n][d].
// ---------------------------------------------------------------------------
__global__ __launch_bounds__(256) void meanx_kernel(
    const float* __restrict__ x, float* __restrict__ sx)
{
    const int b  = blockIdx.y;
    const int n0 = blockIdx.x * 16;
    const int d0 = threadIdx.x;          // cols d0 and d0+256
    float s0 = 0.f, s1 = 0.f;
    const float* base = x + ((size_t)b * NN + n0) * DD;
#pragma unroll
    for (int n = 0; n < 16; ++n) {
        s0 += base[n * DD + d0];
        s1 += base[n * DD + d0 + 256];
    }
    atomicAdd(&sx[b * DD + d0], s0);
    atomicAdd(&sx[b * DD + d0 + 256], s1);
}

// ---------------------------------------------------------------------------
// Kernel 0c: mean_v[b][e] = Wv[e,:].(sx[b,:]/2048) + bv[e]  (fp32 exact).
// ---------------------------------------------------------------------------
__global__ __launch_bounds__(256) void mvgemv_kernel(
    const float* __restrict__ Wv, const float* __restrict__ bv,
    const float* __restrict__ sx, float* __restrict__ mean_v)
{
    const int blk = blockIdx.x;          // 0..1023
    const int b   = blk >> 7;
    const int e   = (blk & 127) * 4 + (threadIdx.x >> 6);
    const int lane = threadIdx.x & 63;
    const float* wr = Wv + (size_t)e * DD + lane * 8;
    const float* xr = sx + b * DD + lane * 8;
    float s = 0.f;
    for (int j = 0; j < 8; ++j) s += wr[j] * xr[j];
    for (int off = 32; off > 0; off >>= 1) s += __shfl_xor(s, off);
    if (lane == 0)
        mean_v[b * DD + e] = s * (1.0f / 2048.0f) + bv[e];
}

// ---------------------------------------------------------------------------
// Kernel 1: Q/K projection (fp16 inputs, m97 staging).
// ---------------------------------------------------------------------------
__global__ __launch_bounds__(256) void projqk_kernel(
    const _Float16* __restrict__ xh,
    const _Float16* __restrict__ wqh, const _Float16* __restrict__ wkh,
    const float* __restrict__ bq, const float* __restrict__ bk,
    const int* __restrict__ lens,
    _Float16* __restrict__ qb, _Float16* __restrict__ kb)
{
    const int z = blockIdx.z;                       // 0=q 1=k
    const int r0 = blockIdx.y * 128;                // global row in [0,16384)
    const int bb = r0 >> 11;                        // batch
    if ((r0 & 2047) >= lens[bb]) return;            // rows never read
    const _Float16* Wh  = z ? wkh : wqh;
    const float*    bias= z ? bk  : bq;
    _Float16*       outp= z ? kb  : qb;
    const int c0 = blockIdx.x * 128;

    __shared__ __align__(16) _Float16 As[128 * 32];
    __shared__ __align__(16) _Float16 Bs[128 * 32];

    const int tid  = threadIdx.x;
    const int lane = tid & 63;
    const int w    = tid >> 6;
    const int wm   = w >> 1, wn = w & 1;
    const int lr   = lane & 15;
    const int quad = lane >> 4;

    floatx4 zero; zero[0]=0.f; zero[1]=0.f; zero[2]=0.f; zero[3]=0.f;
    floatx4 acc[4][4];
    for (int i = 0; i < 4; ++i)
        for (int j = 0; j < 4; ++j) acc[i][j] = zero;

    for (int kt = 0; kt < DD / 32; ++kt) {
        __syncthreads();
        stage_tile(xh + (size_t)r0 * DD + kt * 32, DD, As, w, lane);
        stage_tile(Wh + (size_t)c0 * DD + kt * 32, DD, Bs, w, lane);
        __syncthreads();
        half8 a[4], b[4];
        for (int mt = 0; mt < 4; ++mt) a[mt] = frag(As, wm * 64 + mt * 16 + lr, quad);
        for (int nt = 0; nt < 4; ++nt) b[nt] = frag(Bs, wn * 64 + nt * 16 + lr, quad);
        for (int mt = 0; mt < 4; ++mt)
            for (int nt = 0; nt < 4; ++nt)
                acc[mt][nt] = __builtin_amdgcn_mfma_f32_16x16x32_f16(a[mt], b[nt], acc[mt][nt], 0, 0, 0);
    }

    for (int mt = 0; mt < 4; ++mt)
        for (int nt = 0; nt < 4; ++nt)
            for (int r = 0; r < 4; ++r) {
                int row = r0 + wm * 64 + mt * 16 + quad * 4 + r;
                int col = c0 + wn * 64 + nt * 16 + lr;
                outp[(size_t)row * DD + col] = (_Float16)(acc[mt][nt][r] + bias[col]);
            }
}

// ---------------------------------------------------------------------------
// Kernel 1b: V projection, TRANSPOSED output, tiles with n0 < L only.
// ---------------------------------------------------------------------------
__global__ __launch_bounds__(256) void projv_kernel(
    const _Float16* __restrict__ xh,
    const _Float16* __restrict__ wvh, const float* __restrict__ bv,
    const int* __restrict__ lens, _Float16* __restrict__ vhT)
{
    const int b  = blockIdx.z;
    const int e0 = blockIdx.y * 128;
    const int n0 = blockIdx.x * 128;
    if (n0 >= lens[b]) return;

    __shared__ __align__(16) _Float16 As[128 * 32];
    __shared__ __align__(16) _Float16 Bs[128 * 32];

    const int tid  = threadIdx.x;
    const int lane = tid & 63;
    const int w    = tid >> 6;
    const int wm   = w >> 1, wn = w & 1;
    const int lr   = lane & 15;
    const int quad = lane >> 4;

    floatx4 zero; zero[0]=0.f; zero[1]=0.f; zero[2]=0.f; zero[3]=0.f;
    floatx4 acc[4][4];
    for (int i = 0; i < 4; ++i)
        for (int j = 0; j < 4; ++j) acc[i][j] = zero;

    for (int kt = 0; kt < DD / 32; ++kt) {
        __syncthreads();
        stage_tile(wvh + (size_t)e0 * DD + kt * 32, DD, As, w, lane);
        stage_tile(xh + ((size_t)b * NN + n0) * DD + kt * 32, DD, Bs, w, lane);
        __syncthreads();
        half8 a[4], bfr[4];
        for (int mt = 0; mt < 4; ++mt) a[mt]   = frag(As, wm * 64 + mt * 16 + lr, quad);
        for (int nt = 0; nt < 4; ++nt) bfr[nt] = frag(Bs, wn * 64 + nt * 16 + lr, quad);
        for (int mt = 0; mt < 4; ++mt)
            for (int nt = 0; nt < 4; ++nt)
                acc[mt][nt] = __builtin_amdgcn_mfma_f32_16x16x32_f16(a[mt], bfr[nt], acc[mt][nt], 0, 0, 0);
    }

    for (int mt = 0; mt < 4; ++mt)
        for (int nt = 0; nt < 4; ++nt)
            for (int r = 0; r < 4; ++r) {
                int e = e0 + wm * 64 + mt * 16 + quad * 4 + r;
                int n = n0 + wn * 64 + nt * 16 + lr;
                vhT[((size_t)b * DD + e) * NN + n] = (_Float16)(acc[mt][nt][r] + bv[e]);
            }
}

// ---------------------------------------------------------------------------
// Kernel 2: S = (Q.K^T)/sqrt(512) -> fp16.  REGISTER-DIRECT, barrier-free;
// static trip count, forced unroll -> all fragment indices static.
// ---------------------------------------------------------------------------
__global__ __launch_bounds__(256) void scores_kernel(
    const _Float16* __restrict__ qb, const _Float16* __restrict__ kb,
    const int* __restrict__ lens, _Float16* __restrict__ S)
{
    const int b  = blockIdx.z;
    const int r0 = blockIdx.y * 128;
    const int c0 = blockIdx.x * 128;
    const int L  = lens[b];
    if (r0 >= L || c0 >= L) return;

    const int tid  = threadIdx.x;
    const int lane = tid & 63;
    const int w    = tid >> 6;
    const int wm   = w >> 1, wn = w & 1;
    const int lr   = lane & 15;
    const int quad = lane >> 4;

    const _Float16* Ap = qb + ((size_t)b * NN + r0 + wm * 64 + lr) * DD + quad * 8;
    const _Float16* Bp = kb + ((size_t)b * NN + c0 + wn * 64 + lr) * DD + quad * 8;

    floatx4 zero; zero[0]=0.f; zero[1]=0.f; zero[2]=0.f; zero[3]=0.f;
    floatx4 acc[4][4];
    for (int i = 0; i < 4; ++i)
        for (int j = 0; j < 4; ++j) acc[i][j] = zero;

    half8 a[2][4], bf[2][4];
#pragma unroll
    for (int mt = 0; mt < 4; ++mt) a[0][mt]  = *(const half8*)&Ap[(size_t)(mt * 16) * DD];
#pragma unroll
    for (int nt = 0; nt < 4; ++nt) bf[0][nt] = *(const half8*)&Bp[(size_t)(nt * 16) * DD];

#pragma unroll
    for (int kt = 0; kt < DD / 32; ++kt) {
        const int cur = kt & 1;
        if (kt + 1 < DD / 32) {
#pragma unroll
            for (int mt = 0; mt < 4; ++mt)
                a[cur ^ 1][mt]  = *(const half8*)&Ap[(size_t)(mt * 16) * DD + (kt + 1) * 32];
#pragma unroll
            for (int nt = 0; nt < 4; ++nt)
                bf[cur ^ 1][nt] = *(const half8*)&Bp[(size_t)(nt * 16) * DD + (kt + 1) * 32];
        }
#pragma unroll
        for (int mt = 0; mt < 4; ++mt)
#pragma unroll
            for (int nt = 0; nt < 4; ++nt)
                acc[mt][nt] = __builtin_amdgcn_mfma_f32_16x16x32_f16(a[cur][mt], bf[cur][nt], acc[mt][nt], 0, 0, 0);
    }

    const float scale = 0.044194173824159216f;   // 1/sqrt(512)
    for (int mt = 0; mt < 4; ++mt)
        for (int nt = 0; nt < 4; ++nt)
            for (int r = 0; r < 4; ++r) {
                int q    = r0 + wm * 64 + mt * 16 + quad * 4 + r;
                int kcol = c0 + wn * 64 + nt * 16 + lr;
                S[((size_t)b * NN + q) * NN + kcol] = (_Float16)(acc[mt][nt][r] * scale);
            }
}

// ---------------------------------------------------------------------------
// Kernel 3: in-place row softmax, rows q<L, keys k<L; writes P=0 for
// k in [L, ceil32(L)) so pv's last K-chunk is clean.
// ---------------------------------------------------------------------------
__global__ __launch_bounds__(256) void softmax_kernel(
    _Float16* __restrict__ S, const int* __restrict__ lens)
{
    const int b = blockIdx.y, q = blockIdx.x;
    const int L = lens[b];
    if (q >= L) return;
    const int Lp32 = (L + 31) & ~31;
    const size_t base = ((size_t)b * NN + q) * NN;
    const int tid  = threadIdx.x;
    const int lane = tid & 63;
    const int w    = tid >> 6;
    const int k0   = tid * 8;
    const bool active = k0 < Lp32;
    const float NEG = -__builtin_huge_valf();

    float f[8];
    if (active) {
        half8 v = *(const half8*)&S[base + k0];
        for (int j = 0; j < 8; ++j) f[j] = (k0 + j < L) ? (float)v[j] : NEG;
    } else {
        for (int j = 0; j < 8; ++j) f[j] = NEG;
    }

    float m = f[0];
    for (int j = 1; j < 8; ++j) m = fmaxf(m, f[j]);
    for (int off = 32; off > 0; off >>= 1) m = fmaxf(m, __shfl_xor(m, off));
    __shared__ float redm[4];
    __shared__ float reds[4];
    if (lane == 0) redm[w] = m;
    __syncthreads();
    m = fmaxf(fmaxf(redm[0], redm[1]), fmaxf(redm[2], redm[3]));

    float e[8], s = 0.f;
    for (int j = 0; j < 8; ++j) { e[j] = __expf(f[j] - m); s += e[j]; }  // exp(-inf)=0
    for (int off = 32; off > 0; off >>= 1) s += __shfl_xor(s, off);
    if (lane == 0) reds[w] = s;
    __syncthreads();
    s = (reds[0] + reds[1]) + (reds[2] + reds[3]);

    float inv = 1.0f / s;
    if (active) {
        half8 o;
        for (int j = 0; j < 8; ++j) o[j] = (_Float16)(e[j] * inv);
        *(half8*)&S[base + k0] = o;
    }
}

// ---------------------------------------------------------------------------
// Kernel 4: O[b][q][e] = sum_{k<L} P[b][q][k] * Vt[b][e][k] for q<L;
// mean_v for q>=L.  REGISTER-DIRECT, barrier-free, runtime trip count ->
// EXPLICIT unroll-by-2 with named buffer sets a0/b0, a1/b1 (static indices,
// no scratch spill — R9 post-mortem).  64-row q-tiles; wave w owns e-cols
// c0+32w..+31.
// ---------------------------------------------------------------------------
__global__ __launch_bounds__(256) void pv_kernel(
    const _Float16* __restrict__ P, const _Float16* __restrict__ vhT,
    const int* __restrict__ lens, const float* __restrict__ mean_v,
    float* __restrict__ out)
{
    const int b  = blockIdx.z;
    const int L  = lens[b];
    const int r0 = blockIdx.y * 64;    // q rows
    const int c0 = blockIdx.x * 128;   // e cols
    const int KT = (r0 < L) ? ((L + 31) >> 5) : 0;

    const int tid  = threadIdx.x;
    const int lane = tid & 63;
    const int w    = tid >> 6;
    const int lr   = lane & 15;
    const int quad = lane >> 4;

    const _Float16* Ap = P   + ((size_t)b * NN + r0 + lr) * NN + quad * 8;
    const _Float16* Bp = vhT + ((size_t)b * DD + c0 + w * 32 + lr) * NN + quad * 8;

    floatx4 zero; zero[0]=0.f; zero[1]=0.f; zero[2]=0.f; zero[3]=0.f;
    floatx4 acc[4][2];
    for (int i = 0; i < 4; ++i)
        for (int j = 0; j < 2; ++j) acc[i][j] = zero;

    half8 a0[4], b0[2], a1[4], b1[2];
    if (KT > 0) {
#pragma unroll
        for (int mt = 0; mt < 4; ++mt) a0[mt] = *(const half8*)&Ap[(size_t)(mt * 16) * NN];
#pragma unroll
        for (int nt = 0; nt < 2; ++nt) b0[nt] = *(const half8*)&Bp[(size_t)(nt * 16) * NN];
    }
    for (int kt = 0; kt < KT; kt += 2) {
        if (kt + 1 < KT) {
#pragma unroll
            for (int mt = 0; mt < 4; ++mt)
                a1[mt] = *(const half8*)&Ap[(size_t)(mt * 16) * NN + (kt + 1) * 32];
#pragma unroll
            for (int nt = 0; nt < 2; ++nt)
                b1[nt] = *(const half8*)&Bp[(size_t)(nt * 16) * NN + (kt + 1) * 32];
        }
#pragma unroll
        for (int mt = 0; mt < 4; ++mt)
#pragma unroll
            for (int nt = 0; nt < 2; ++nt)
                acc[mt][nt] = __builtin_amdgcn_mfma_f32_16x16x32_f16(a0[mt], b0[nt], acc[mt][nt], 0, 0, 0);
        if (kt + 1 < KT) {
            if (kt + 2 < KT) {
#pragma unroll
                for (int mt = 0; mt < 4; ++mt)
                    a0[mt] = *(const half8*)&Ap[(size_t)(mt * 16) * NN + (kt + 2) * 32];
#pragma unroll
                for (int nt = 0; nt < 2; ++nt)
                    b0[nt] = *(const half8*)&Bp[(size_t)(nt * 16) * NN + (kt + 2) * 32];
            }
#pragma unroll
            for (int mt = 0; mt < 4; ++mt)
#pragma unroll
                for (int nt = 0; nt < 2; ++nt)
                    acc[mt][nt] = __builtin_amdgcn_mfma_f32_16x16x32_f16(a1[mt], b1[nt], acc[mt][nt], 0, 0, 0);
        }
    }

    float mval[2];
    for (int nt = 0; nt < 2; ++nt)
        mval[nt] = mean_v[b * DD + c0 + w * 32 + nt * 16 + lr];

    for (int mt = 0; mt < 4; ++mt)
        for (int nt = 0; nt < 2; ++nt)
            for (int r = 0; r < 4; ++r) {
                int q = r0 + mt * 16 + quad * 4 + r;
                int e = c0 + w * 32 + nt * 16 + lr;
                float val = (q < L) ? acc[mt][nt][r] : mval[nt];
                out[((size_t)b * NN + q) * DD + e] = val;
            }
}

// ---------------------------------------------------------------------------
extern "C" void kernel_launch(void* const* d_in, const int* in_sizes, int n_in,
                              void* d_out, int out_size, void* d_ws, size_t ws_size,
                              hipStream_t stream) {
    const float* x    = (const float*)d_in[0];
    const int*   lens = (const int*)d_in[1];   // harness delivers integer inputs as int32
    const float* Wq   = (const float*)d_in[2];
    const float* bq   = (const float*)d_in[3];
    const float* Wk   = (const float*)d_in[4];
    const float* bk   = (const float*)d_in[5];
    const float* Wv   = (const float*)d_in[6];
    const float* bv   = (const float*)d_in[7];
    float* out = (float*)d_out;

    // workspace layout (128 MiB):
    //   0: qb (16M) | 16M: kb (16M) | 32M: vhT (16M)
    //   48M: mean_v (16KB) | 48M+64K: sx (16KB)
    //   64M: S (64M) — first ~18M overlaid by [xh 16M | wqh | wkh | wvh],
    //        dead before scores_kernel writes S (stream-ordered).
    char* ws = (char*)d_ws;
    const size_t MB = 1024 * 1024;
    _Float16* qb  = (_Float16*)(ws);
    _Float16* kb  = (_Float16*)(ws + 16 * MB);
    _Float16* vh  = (_Float16*)(ws + 32 * MB);
    float*    mv  = (float*)   (ws + 48 * MB);
    float*    sx  = (float*)   (ws + 48 * MB + 64 * 1024);
    _Float16* S   = (_Float16*)(ws + 64 * MB);
    _Float16* xh  = (_Float16*)(ws + 64 * MB);
    _Float16* wqh = (_Float16*)(ws + 80 * MB);
    _Float16* wkh = (_Float16*)(ws + 80 * MB + 512 * 1024);
    _Float16* wvh = (_Float16*)(ws + 81 * MB);

    hipMemsetAsync(sx, 0, BB * DD * sizeof(float), stream);
    prep_kernel  <<<8960, 256, 0, stream>>>(x, Wq, Wk, Wv, lens, xh, wqh, wkh, wvh);
    meanx_kernel <<<dim3(128, 8),    256, 0, stream>>>(x, sx);
    mvgemv_kernel<<<1024,            256, 0, stream>>>(Wv, bv, sx, mv);
    projqk_kernel<<<dim3(4, 128, 2), 256, 0, stream>>>(xh, wqh, wkh, bq, bk, lens, qb, kb);
    projv_kernel <<<dim3(16, 4, 8),  256, 0, stream>>>(xh, wvh, bv, lens, vh);
    scores_kernel<<<dim3(16, 16, 8), 256, 0, stream>>>(qb, kb, lens, S);
    softmax_kernel<<<dim3(2048, 8),  256, 0, stream>>>(S, lens);
    pv_kernel    <<<dim3(4, 32, 8),  256, 0, stream>>>(S, vh, lens, mv, out);
}

// Round 11
// 211.901 us; speedup vs baseline: 17.6767x; 1.5343x over previous
//
#include <hip/hip_runtime.h>

typedef _Float16 half8 __attribute__((ext_vector_type(8)));
typedef _Float16 half4 __attribute__((ext_vector_type(4)));
typedef float    floatx4 __attribute__((ext_vector_type(4)));
typedef float    float4v __attribute__((ext_vector_type(4)));

#define BB 8
#define NN 2048
#define DD 512

// MFMA fragment mapping (gfx950, 16x16x32, m89/m91/m120-verified):
//   A-operand: A[m = lane&15][k = (lane>>4)*8 + j], j=0..7 contiguous
//   B-operand: B[n = lane&15][k = (lane>>4)*8 + j]   (NT: both contiguous in k)
//   C/D:       col = lane&15, row = (lane>>4)*4 + reg
//
// R11 = measured best-of assembly.  R9/R10 post-mortem: register-direct
// GEMMs (no LDS) lose 2.5x to global_load_lds staging at this occupancy —
// depth-1 register prefetch covers ~50 cyc vs ~200-900 cyc load latency.
// All GEMMs use m97 staging (XOR swizzle, SQ_LDS_BANK_CONFLICT==0 measured).
//
// Length-aware sparsity: only the (q<L)x(k<L) region is computed.  Rows
// q>=L get mean(v) exactly via mean_v = Wv*mean_x + bv (linearity), written
// in pv's epilogue.

__device__ __forceinline__ void stage_tile(const _Float16* __restrict__ g,
                                           int gstride, _Float16* lds,
                                           int w, int lane)
{
#pragma unroll
    for (int j = 0; j < 2; ++j) {
        int grp = w * 2 + j;                      // 16-row group 0..7
        int r   = grp * 16 + (lane >> 2);         // 0..127
        int cb  = (lane & 3) ^ ((r >> 1) & 3);    // logical 16B block to fetch
        const _Float16* gp = g + (size_t)r * gstride + cb * 8;
        _Float16* lp = lds + grp * 512;           // wave-uniform base
        __builtin_amdgcn_global_load_lds(
            (const __attribute__((address_space(1))) void*)gp,
            (__attribute__((address_space(3))) void*)lp, 16, 0, 0);
    }
}

// 64-row variant: one load per thread.
__device__ __forceinline__ void stage_tile64(const _Float16* __restrict__ g,
                                             int gstride, _Float16* lds,
                                             int w, int lane)
{
    int r  = w * 16 + (lane >> 2);                // 0..63
    int cb = (lane & 3) ^ ((r >> 1) & 3);
    const _Float16* gp = g + (size_t)r * gstride + cb * 8;
    _Float16* lp = lds + w * 512;                 // wave-uniform base
    __builtin_amdgcn_global_load_lds(
        (const __attribute__((address_space(1))) void*)gp,
        (__attribute__((address_space(3))) void*)lp, 16, 0, 0);
}

__device__ __forceinline__ half8 frag(const _Float16* tile, int m, int quad)
{
    return *(const half8*)&tile[m * 32 + ((quad ^ ((m >> 1) & 3)) * 8)];
}

// ---------------------------------------------------------------------------
// Kernel 0: prep — fp16 copies of x, Wq, Wk, Wv.  x rows >= ceil128(L) are
// never read by projqk/projv -> skipped.
// ---------------------------------------------------------------------------
__global__ __launch_bounds__(256) void prep_kernel(
    const float* __restrict__ x, const float* __restrict__ Wq,
    const float* __restrict__ Wk, const float* __restrict__ Wv,
    const int* __restrict__ lens,
    _Float16* __restrict__ xh, _Float16* __restrict__ wqh,
    _Float16* __restrict__ wkh, _Float16* __restrict__ wvh)
{
    const int XQ = (BB * NN * DD) / 4;   // 2097152 float4s
    const int WQ = (DD * DD) / 4;        // 65536
    int t = blockIdx.x * 256 + threadIdx.x;
    const float* src; _Float16* dst; int i;
    if (t < XQ) {
        int row = t >> 7;                // 128 float4 per row
        int b   = row >> 11;
        if ((row & 2047) >= ((lens[b] + 127) & ~127)) return;
        src = x;  dst = xh;  i = t;
    }
    else if (t < XQ + WQ)   { src = Wq; dst = wqh; i = t - XQ; }
    else if (t < XQ + 2*WQ) { src = Wk; dst = wkh; i = t - XQ - WQ; }
    else if (t < XQ + 3*WQ) { src = Wv; dst = wvh; i = t - XQ - 2*WQ; }
    else return;
    float4v f = *(const float4v*)&src[(size_t)i * 4];
    half4 h;
    for (int j = 0; j < 4; ++j) h[j] = (_Float16)f[j];
    *(half4*)&dst[(size_t)i * 4] = h;
}

// ---------------------------------------------------------------------------
// Kernel 0b: column sums of x (fp32, exact): sx[b][d] = sum_n x[b][n][d].
// 1024 blocks (16 rows each); sx pre-zeroed by memset.
// ---------------------------------------------------------------------------
__global__ __launch_bounds__(256) void meanx_kernel(
    const float* __restrict__ x, float* __restrict__ sx)
{
    const int b  = blockIdx.y;
    const int n0 = blockIdx.x * 16;
    const int d0 = threadIdx.x;          // cols d0 and d0+256
    float s0 = 0.f, s1 = 0.f;
    const float* base = x + ((size_t)b * NN + n0) * DD;
#pragma unroll
    for (int n = 0; n < 16; ++n) {
        s0 += base[n * DD + d0];
        s1 += base[n * DD + d0 + 256];
    }
    atomicAdd(&sx[b * DD + d0], s0);
    atomicAdd(&sx[b * DD + d0 + 256], s1);
}

// ---------------------------------------------------------------------------
// Kernel 0c: mean_v[b][e] = Wv[e,:].(sx[b,:]/2048) + bv[e]  (fp32 exact).
// ---------------------------------------------------------------------------
__global__ __launch_bounds__(256) void mvgemv_kernel(
    const float* __restrict__ Wv, const float* __restrict__ bv,
    const float* __restrict__ sx, float* __restrict__ mean_v)
{
    const int blk = blockIdx.x;          // 0..1023
    const int b   = blk >> 7;
    const int e   = (blk & 127) * 4 + (threadIdx.x >> 6);
    const int lane = threadIdx.x & 63;
    const float* wr = Wv + (size_t)e * DD + lane * 8;
    const float* xr = sx + b * DD + lane * 8;
    float s = 0.f;
    for (int j = 0; j < 8; ++j) s += wr[j] * xr[j];
    for (int off = 32; off > 0; off >>= 1) s += __shfl_xor(s, off);
    if (lane == 0)
        mean_v[b * DD + e] = s * (1.0f / 2048.0f) + bv[e];
}

// ---------------------------------------------------------------------------
// Kernel 1: Q/K projection (fp16 inputs, m97 staging).
// ---------------------------------------------------------------------------
__global__ __launch_bounds__(256) void projqk_kernel(
    const _Float16* __restrict__ xh,
    const _Float16* __restrict__ wqh, const _Float16* __restrict__ wkh,
    const float* __restrict__ bq, const float* __restrict__ bk,
    const int* __restrict__ lens,
    _Float16* __restrict__ qb, _Float16* __restrict__ kb)
{
    const int z = blockIdx.z;                       // 0=q 1=k
    const int r0 = blockIdx.y * 128;                // global row in [0,16384)
    const int bb = r0 >> 11;                        // batch
    if ((r0 & 2047) >= lens[bb]) return;            // rows never read
    const _Float16* Wh  = z ? wkh : wqh;
    const float*    bias= z ? bk  : bq;
    _Float16*       outp= z ? kb  : qb;
    const int c0 = blockIdx.x * 128;

    __shared__ __align__(16) _Float16 As[128 * 32];
    __shared__ __align__(16) _Float16 Bs[128 * 32];

    const int tid  = threadIdx.x;
    const int lane = tid & 63;
    const int w    = tid >> 6;
    const int wm   = w >> 1, wn = w & 1;
    const int lr   = lane & 15;
    const int quad = lane >> 4;

    floatx4 zero; zero[0]=0.f; zero[1]=0.f; zero[2]=0.f; zero[3]=0.f;
    floatx4 acc[4][4];
    for (int i = 0; i < 4; ++i)
        for (int j = 0; j < 4; ++j) acc[i][j] = zero;

    for (int kt = 0; kt < DD / 32; ++kt) {
        __syncthreads();
        stage_tile(xh + (size_t)r0 * DD + kt * 32, DD, As, w, lane);
        stage_tile(Wh + (size_t)c0 * DD + kt * 32, DD, Bs, w, lane);
        __syncthreads();
        half8 a[4], b[4];
        for (int mt = 0; mt < 4; ++mt) a[mt] = frag(As, wm * 64 + mt * 16 + lr, quad);
        for (int nt = 0; nt < 4; ++nt) b[nt] = frag(Bs, wn * 64 + nt * 16 + lr, quad);
        for (int mt = 0; mt < 4; ++mt)
            for (int nt = 0; nt < 4; ++nt)
                acc[mt][nt] = __builtin_amdgcn_mfma_f32_16x16x32_f16(a[mt], b[nt], acc[mt][nt], 0, 0, 0);
    }

    for (int mt = 0; mt < 4; ++mt)
        for (int nt = 0; nt < 4; ++nt)
            for (int r = 0; r < 4; ++r) {
                int row = r0 + wm * 64 + mt * 16 + quad * 4 + r;
                int col = c0 + wn * 64 + nt * 16 + lr;
                outp[(size_t)row * DD + col] = (_Float16)(acc[mt][nt][r] + bias[col]);
            }
}

// ---------------------------------------------------------------------------
// Kernel 1b: V projection, TRANSPOSED output, tiles with n0 < L only.
// ---------------------------------------------------------------------------
__global__ __launch_bounds__(256) void projv_kernel(
    const _Float16* __restrict__ xh,
    const _Float16* __restrict__ wvh, const float* __restrict__ bv,
    const int* __restrict__ lens, _Float16* __restrict__ vhT)
{
    const int b  = blockIdx.z;
    const int e0 = blockIdx.y * 128;
    const int n0 = blockIdx.x * 128;
    if (n0 >= lens[b]) return;

    __shared__ __align__(16) _Float16 As[128 * 32];
    __shared__ __align__(16) _Float16 Bs[128 * 32];

    const int tid  = threadIdx.x;
    const int lane = tid & 63;
    const int w    = tid >> 6;
    const int wm   = w >> 1, wn = w & 1;
    const int lr   = lane & 15;
    const int quad = lane >> 4;

    floatx4 zero; zero[0]=0.f; zero[1]=0.f; zero[2]=0.f; zero[3]=0.f;
    floatx4 acc[4][4];
    for (int i = 0; i < 4; ++i)
        for (int j = 0; j < 4; ++j) acc[i][j] = zero;

    for (int kt = 0; kt < DD / 32; ++kt) {
        __syncthreads();
        stage_tile(wvh + (size_t)e0 * DD + kt * 32, DD, As, w, lane);
        stage_tile(xh + ((size_t)b * NN + n0) * DD + kt * 32, DD, Bs, w, lane);
        __syncthreads();
        half8 a[4], bfr[4];
        for (int mt = 0; mt < 4; ++mt) a[mt]   = frag(As, wm * 64 + mt * 16 + lr, quad);
        for (int nt = 0; nt < 4; ++nt) bfr[nt] = frag(Bs, wn * 64 + nt * 16 + lr, quad);
        for (int mt = 0; mt < 4; ++mt)
            for (int nt = 0; nt < 4; ++nt)
                acc[mt][nt] = __builtin_amdgcn_mfma_f32_16x16x32_f16(a[mt], bfr[nt], acc[mt][nt], 0, 0, 0);
    }

    for (int mt = 0; mt < 4; ++mt)
        for (int nt = 0; nt < 4; ++nt)
            for (int r = 0; r < 4; ++r) {
                int e = e0 + wm * 64 + mt * 16 + quad * 4 + r;
                int n = n0 + wn * 64 + nt * 16 + lr;
                vhT[((size_t)b * DD + e) * NN + n] = (_Float16)(acc[mt][nt][r] + bv[e]);
            }
}

// ---------------------------------------------------------------------------
// Kernel 2: S = (Q.K^T)/sqrt(512) -> fp16, only tiles with r0<L && c0<L
// (m97 LDS staging — measured faster than register-direct at this occupancy).
// ---------------------------------------------------------------------------
__global__ __launch_bounds__(256) void scores_kernel(
    const _Float16* __restrict__ qb, const _Float16* __restrict__ kb,
    const int* __restrict__ lens, _Float16* __restrict__ S)
{
    const int b  = blockIdx.z;
    const int r0 = blockIdx.y * 128;
    const int c0 = blockIdx.x * 128;
    const int L  = lens[b];
    if (r0 >= L || c0 >= L) return;
    const _Float16* A  = qb + (size_t)b * NN * DD;
    const _Float16* Bm = kb + (size_t)b * NN * DD;

    __shared__ __align__(16) _Float16 As[128 * 32];
    __shared__ __align__(16) _Float16 Bs[128 * 32];

    const int tid  = threadIdx.x;
    const int lane = tid & 63;
    const int w    = tid >> 6;
    const int wm   = w >> 1, wn = w & 1;
    const int lr   = lane & 15;
    const int quad = lane >> 4;

    floatx4 zero; zero[0]=0.f; zero[1]=0.f; zero[2]=0.f; zero[3]=0.f;
    floatx4 acc[4][4];
    for (int i = 0; i < 4; ++i)
        for (int j = 0; j < 4; ++j) acc[i][j] = zero;

    for (int kt = 0; kt < DD / 32; ++kt) {
        __syncthreads();
        stage_tile(A  + (size_t)r0 * DD + kt * 32, DD, As, w, lane);
        stage_tile(Bm + (size_t)c0 * DD + kt * 32, DD, Bs, w, lane);
        __syncthreads();
        half8 a[4], bfr[4];
        for (int mt = 0; mt < 4; ++mt) a[mt]   = frag(As, wm * 64 + mt * 16 + lr, quad);
        for (int nt = 0; nt < 4; ++nt) bfr[nt] = frag(Bs, wn * 64 + nt * 16 + lr, quad);
        for (int mt = 0; mt < 4; ++mt)
            for (int nt = 0; nt < 4; ++nt)
                acc[mt][nt] = __builtin_amdgcn_mfma_f32_16x16x32_f16(a[mt], bfr[nt], acc[mt][nt], 0, 0, 0);
    }

    const float scale = 0.044194173824159216f;   // 1/sqrt(512)
    for (int mt = 0; mt < 4; ++mt)
        for (int nt = 0; nt < 4; ++nt)
            for (int r = 0; r < 4; ++r) {
                int q    = r0 + wm * 64 + mt * 16 + quad * 4 + r;
                int kcol = c0 + wn * 64 + nt * 16 + lr;
                S[((size_t)b * NN + q) * NN + kcol] = (_Float16)(acc[mt][nt][r] * scale);
            }
}

// ---------------------------------------------------------------------------
// Kernel 3: in-place row softmax, rows q<L, keys k<L; writes P=0 for
// k in [L, ceil32(L)) so pv's last K-chunk is clean.
// ---------------------------------------------------------------------------
__global__ __launch_bounds__(256) void softmax_kernel(
    _Float16* __restrict__ S, const int* __restrict__ lens)
{
    const int b = blockIdx.y, q = blockIdx.x;
    const int L = lens[b];
    if (q >= L) return;
    const int Lp32 = (L + 31) & ~31;
    const size_t base = ((size_t)b * NN + q) * NN;
    const int tid  = threadIdx.x;
    const int lane = tid & 63;
    const int w    = tid >> 6;
    const int k0   = tid * 8;
    const bool active = k0 < Lp32;
    const float NEG = -__builtin_huge_valf();

    float f[8];
    if (active) {
        half8 v = *(const half8*)&S[base + k0];
        for (int j = 0; j < 8; ++j) f[j] = (k0 + j < L) ? (float)v[j] : NEG;
    } else {
        for (int j = 0; j < 8; ++j) f[j] = NEG;
    }

    float m = f[0];
    for (int j = 1; j < 8; ++j) m = fmaxf(m, f[j]);
    for (int off = 32; off > 0; off >>= 1) m = fmaxf(m, __shfl_xor(m, off));
    __shared__ float redm[4];
    __shared__ float reds[4];
    if (lane == 0) redm[w] = m;
    __syncthreads();
    m = fmaxf(fmaxf(redm[0], redm[1]), fmaxf(redm[2], redm[3]));

    float e[8], s = 0.f;
    for (int j = 0; j < 8; ++j) { e[j] = __expf(f[j] - m); s += e[j]; }  // exp(-inf)=0
    for (int off = 32; off > 0; off >>= 1) s += __shfl_xor(s, off);
    if (lane == 0) reds[w] = s;
    __syncthreads();
    s = (reds[0] + reds[1]) + (reds[2] + reds[3]);

    float inv = 1.0f / s;
    if (active) {
        half8 o;
        for (int j = 0; j < 8; ++j) o[j] = (_Float16)(e[j] * inv);
        *(half8*)&S[base + k0] = o;
    }
}

// ---------------------------------------------------------------------------
// Kernel 4: O[b][q][e] = sum_{k<L} P[b][q][k] * Vt[b][e][k] for q<L;
// mean_v for q>=L.  64-row q-tiles; LDS double-buffered staging (measured
// best: 41 µs).  Wave w owns e-cols c0+32w..+31.
// ---------------------------------------------------------------------------
__global__ __launch_bounds__(256) void pv_kernel(
    const _Float16* __restrict__ P, const _Float16* __restrict__ vhT,
    const int* __restrict__ lens, const float* __restrict__ mean_v,
    float* __restrict__ out)
{
    const int b  = blockIdx.z;
    const int L  = lens[b];
    const int r0 = blockIdx.y * 64;    // q rows (64-row tiles)
    const int c0 = blockIdx.x * 128;   // e cols
    const int KT = (r0 < L) ? ((L + 31) >> 5) : 0;
    const _Float16* A  = P   + (size_t)b * NN * NN;
    const _Float16* Vh = vhT + (size_t)b * DD * NN;

    __shared__ __align__(16) _Float16 As[2][64 * 32];
    __shared__ __align__(16) _Float16 Bhs[2][128 * 32];

    const int tid  = threadIdx.x;
    const int lane = tid & 63;
    const int w    = tid >> 6;
    const int lr   = lane & 15;
    const int quad = lane >> 4;

    floatx4 zero; zero[0]=0.f; zero[1]=0.f; zero[2]=0.f; zero[3]=0.f;
    floatx4 acc[4][2];
    for (int i = 0; i < 4; ++i)
        for (int j = 0; j < 2; ++j) acc[i][j] = zero;

    if (KT > 0) {
        stage_tile64(A + (size_t)r0 * NN, NN, As[0], w, lane);
        stage_tile (Vh + (size_t)c0 * NN, NN, Bhs[0], w, lane);
    }
    for (int kt = 0; kt < KT; ++kt) {
        const int cur = kt & 1;
        __syncthreads();                       // drains loads into cur
        if (kt + 1 < KT) {                     // prefetch next into other buf
            stage_tile64(A + (size_t)r0 * NN + (kt + 1) * 32, NN, As[cur ^ 1], w, lane);
            stage_tile (Vh + (size_t)c0 * NN + (kt + 1) * 32, NN, Bhs[cur ^ 1], w, lane);
        }
        half8 a[4], bh[2];
        for (int mt = 0; mt < 4; ++mt) a[mt]  = frag(As[cur], mt * 16 + lr, quad);
        for (int nt = 0; nt < 2; ++nt) bh[nt] = frag(Bhs[cur], w * 32 + nt * 16 + lr, quad);
        for (int mt = 0; mt < 4; ++mt)
            for (int nt = 0; nt < 2; ++nt)
                acc[mt][nt] = __builtin_amdgcn_mfma_f32_16x16x32_f16(a[mt], bh[nt], acc[mt][nt], 0, 0, 0);
    }

    float mval[2];
    for (int nt = 0; nt < 2; ++nt)
        mval[nt] = mean_v[b * DD + c0 + w * 32 + nt * 16 + lr];

    for (int mt = 0; mt < 4; ++mt)
        for (int nt = 0; nt < 2; ++nt)
            for (int r = 0; r < 4; ++r) {
                int q = r0 + mt * 16 + quad * 4 + r;
                int e = c0 + w * 32 + nt * 16 + lr;
                float val = (q < L) ? acc[mt][nt][r] : mval[nt];
                out[((size_t)b * NN + q) * DD + e] = val;
            }
}

// ---------------------------------------------------------------------------
extern "C" void kernel_launch(void* const* d_in, const int* in_sizes, int n_in,
                              void* d_out, int out_size, void* d_ws, size_t ws_size,
                              hipStream_t stream) {
    const float* x    = (const float*)d_in[0];
    const int*   lens = (const int*)d_in[1];   // harness delivers integer inputs as int32
    const float* Wq   = (const float*)d_in[2];
    const float* bq   = (const float*)d_in[3];
    const float* Wk   = (const float*)d_in[4];
    const float* bk   = (const float*)d_in[5];
    const float* Wv   = (const float*)d_in[6];
    const float* bv   = (const float*)d_in[7];
    float* out = (float*)d_out;

    // workspace layout (128 MiB):
    //   0: qb (16M) | 16M: kb (16M) | 32M: vhT (16M)
    //   48M: mean_v (16KB) | 48M+64K: sx (16KB)
    //   64M: S (64M) — first ~18M overlaid by [xh 16M | wqh | wkh | wvh],
    //        dead before scores_kernel writes S (stream-ordered).
    char* ws = (char*)d_ws;
    const size_t MB = 1024 * 1024;
    _Float16* qb  = (_Float16*)(ws);
    _Float16* kb  = (_Float16*)(ws + 16 * MB);
    _Float16* vh  = (_Float16*)(ws + 32 * MB);
    float*    mv  = (float*)   (ws + 48 * MB);
    float*    sx  = (float*)   (ws + 48 * MB + 64 * 1024);
    _Float16* S   = (_Float16*)(ws + 64 * MB);
    _Float16* xh  = (_Float16*)(ws + 64 * MB);
    _Float16* wqh = (_Float16*)(ws + 80 * MB);
    _Float16* wkh = (_Float16*)(ws + 80 * MB + 512 * 1024);
    _Float16* wvh = (_Float16*)(ws + 81 * MB);

    hipMemsetAsync(sx, 0, BB * DD * sizeof(float), stream);
    prep_kernel  <<<8960, 256, 0, stream>>>(x, Wq, Wk, Wv, lens, xh, wqh, wkh, wvh);
    meanx_kernel <<<dim3(128, 8),    256, 0, stream>>>(x, sx);
    mvgemv_kernel<<<1024,            256, 0, stream>>>(Wv, bv, sx, mv);
    projqk_kernel<<<dim3(4, 128, 2), 256, 0, stream>>>(xh, wqh, wkh, bq, bk, lens, qb, kb);
    projv_kernel <<<dim3(16, 4, 8),  256, 0, stream>>>(xh, wvh, bv, lens, vh);
    scores_kernel<<<dim3(16, 16, 8), 256, 0, stream>>>(qb, kb, lens, S);
    softmax_kernel<<<dim3(2048, 8),  256, 0, stream>>>(S, lens);
    pv_kernel    <<<dim3(4, 32, 8),  256, 0, stream>>>(S, vh, lens, mv, out);
}